// Round 10
// baseline (187.707 us; speedup 1.0000x reference)
//
#include <hip/hip_runtime.h>
#include <hip/hip_bf16.h>

// Problem constants (fixed by the reference module)
static constexpr int B_  = 2;
static constexpr int N_  = 4096;
static constexpr int D_  = 512;
static constexpr int H_  = 8;
static constexpr int P_  = 9;
static constexpr int GH_ = 16;   // grid h
static constexpr int GW_ = 256;  // grid w
static constexpr int M_  = B_ * N_;  // 8192 tokens

typedef __attribute__((ext_vector_type(8))) short bf16x8;
typedef __attribute__((ext_vector_type(4))) float f32x4;

__device__ __forceinline__ unsigned short f2b(float f) {
    __hip_bfloat16 h = __float2bfloat16(f);  // round-to-nearest
    return *reinterpret_cast<unsigned short*>(&h);
}
__device__ __forceinline__ float b2f(unsigned short u) {
    return __uint_as_float(((unsigned int)u) << 16);
}
__device__ __forceinline__ float b2f_lo(unsigned int u) { return __uint_as_float(u << 16); }
__device__ __forceinline__ float b2f_hi(unsigned int u) { return __uint_as_float(u & 0xffff0000u); }

// ---------------------------------------------------------------------------
// Cast fp32 -> bf16 and build the fused weight wall (2304 rows x 512):
//   rows    0..511  Wq | 512..1535 Wkv | 1536..1679 Woff_hi (pad->1791)
//   1792..1935 Woff_lo (pad->2047) | 2048..2191 Woff_hi dup (pad->2303)
__global__ __launch_bounds__(256) void cast_multi(
    const float* __restrict__ x,   const float* __restrict__ wq,
    const float* __restrict__ wkv, const float* __restrict__ wo,
    const float* __restrict__ woff,
    unsigned short* __restrict__ x_hi, unsigned short* __restrict__ x_lo,
    unsigned short* __restrict__ wall, unsigned short* __restrict__ wob) {
    int g = blockIdx.x * 256 + threadIdx.x;

    if (g < 1048576) {  // x -> hi + lo
        float4 v = reinterpret_cast<const float4*>(x)[g];
        ushort4 hi, lo;
        hi.x = f2b(v.x); hi.y = f2b(v.y); hi.z = f2b(v.z); hi.w = f2b(v.w);
        lo.x = f2b(v.x - b2f(hi.x)); lo.y = f2b(v.y - b2f(hi.y));
        lo.z = f2b(v.z - b2f(hi.z)); lo.w = f2b(v.w - b2f(hi.w));
        reinterpret_cast<ushort4*>(x_hi)[g] = hi;
        reinterpret_cast<ushort4*>(x_lo)[g] = lo;
        return;
    }
    g -= 1048576;
    if (g < 65536) {  // Wq -> wall rows 0..511
        float4 v = reinterpret_cast<const float4*>(wq)[g];
        ushort4 o; o.x = f2b(v.x); o.y = f2b(v.y); o.z = f2b(v.z); o.w = f2b(v.w);
        reinterpret_cast<ushort4*>(wall)[g] = o;
        return;
    }
    g -= 65536;
    if (g < 131072) {  // Wkv -> wall rows 512..1535
        float4 v = reinterpret_cast<const float4*>(wkv)[g];
        ushort4 o; o.x = f2b(v.x); o.y = f2b(v.y); o.z = f2b(v.z); o.w = f2b(v.w);
        reinterpret_cast<ushort4*>(wall)[65536 + g] = o;
        return;
    }
    g -= 131072;
    if (g < 65536) {  // Wo -> wob
        float4 v = reinterpret_cast<const float4*>(wo)[g];
        ushort4 o; o.x = f2b(v.x); o.y = f2b(v.y); o.z = f2b(v.z); o.w = f2b(v.w);
        reinterpret_cast<ushort4*>(wob)[g] = o;
        return;
    }
    g -= 65536;
    if (g < 18432) {  // Woff rows 0..143 -> wall hi (1536), lo (1792), hi-dup (2048)
        float4 v = reinterpret_cast<const float4*>(woff)[g];
        ushort4 hi, lo;
        hi.x = f2b(v.x); hi.y = f2b(v.y); hi.z = f2b(v.z); hi.w = f2b(v.w);
        lo.x = f2b(v.x - b2f(hi.x)); lo.y = f2b(v.y - b2f(hi.y));
        lo.z = f2b(v.z - b2f(hi.z)); lo.w = f2b(v.w - b2f(hi.w));
        reinterpret_cast<ushort4*>(wall)[196608 + g] = hi;
        reinterpret_cast<ushort4*>(wall)[229376 + g] = lo;
        reinterpret_cast<ushort4*>(wall)[262144 + g] = hi;
        return;
    }
    g -= 18432;
    // zero pads: rows 1680..1791 / 1936..2047 / 2192..2303 (14336 units each)
    const int which = g / 14336;
    const int idx   = g - which * 14336;
    ushort4 z = {0, 0, 0, 0};
    reinterpret_cast<ushort4*>(wall)[215040 + which * 32768 + idx] = z;
}

// ---------------------------------------------------------------------------
// Double-buffered MFMA GEMM engine. Tile 128(M) x 64(N), BK=64 per stage.
// Two LDS buffer sets (distinct __shared__ arrays so the compiler can prove
// the compute-phase ds_reads don't alias the in-flight prefetch writes):
// per stage, ONE barrier; prefetch for stage s+1 is issued right after the
// barrier and flies while stage s's MFMAs run.
// Each buffer: A = 2 chunks x [128][32] shorts (16 KB), B = 2 x [64][32] (8 KB).

__device__ __forceinline__ void stage_tiles(const unsigned short* pa0,
                                            const unsigned short* pa1,
                                            const unsigned short* pw,
                                            int k0, short* Ab, short* Bb, int wave) {
#pragma unroll
    for (int t = 0; t < 2; ++t) {
        __builtin_amdgcn_global_load_lds(
            (const __attribute__((address_space(1))) void*)(pa0 + k0 + t * 32),
            (__attribute__((address_space(3))) void*)(Ab + t * 4096 + wave * 512),
            16, 0, 0);
        __builtin_amdgcn_global_load_lds(
            (const __attribute__((address_space(1))) void*)(pa1 + k0 + t * 32),
            (__attribute__((address_space(3))) void*)(Ab + t * 4096 + 2048 + wave * 512),
            16, 0, 0);
        __builtin_amdgcn_global_load_lds(
            (const __attribute__((address_space(1))) void*)(pw + k0 + t * 32),
            (__attribute__((address_space(3))) void*)(Bb + t * 2048 + wave * 512),
            16, 0, 0);
    }
}

__device__ __forceinline__ void compute_tiles(const short* Ab, const short* Bb,
                                              f32x4 (&acc)[4][2],
                                              int wm, int wn, int fr, int fk) {
#pragma unroll
    for (int t = 0; t < 2; ++t) {
        bf16x8 af[4], bf[2];
#pragma unroll
        for (int i = 0; i < 4; ++i)
            af[i] = *reinterpret_cast<const bf16x8*>(
                &Ab[t * 4096 + (wm * 64 + i * 16 + fr) * 32 + fk]);
#pragma unroll
        for (int j = 0; j < 2; ++j)
            bf[j] = *reinterpret_cast<const bf16x8*>(
                &Bb[t * 2048 + (wn * 32 + j * 16 + fr) * 32 + fk]);
#pragma unroll
        for (int i = 0; i < 4; ++i)
#pragma unroll
            for (int j = 0; j < 2; ++j)
                acc[i][j] = __builtin_amdgcn_mfma_f32_16x16x32_bf16(
                    af[i], bf[j], acc[i][j], 0, 0, 0);
    }
}

// Kloop must be a multiple of 128 (two BK=64 stages per loop iteration).
__device__ __forceinline__ void gemm_seg_db(const unsigned short* __restrict__ A,
                                            const unsigned short* __restrict__ W,
                                            int m0, int n0, int Kloop, int lda, int ldw,
                                            short* As0, short* As1,
                                            short* Bs0, short* Bs1,
                                            f32x4 (&acc)[4][2], int wave, int lane) {
    const int gi = wave * 64 + lane;        // [0,256)
    const int r0 = gi >> 2, c0 = (gi & 3) * 8;

    const unsigned short* pa0 = A + (size_t)(m0 + r0) * lda + c0;       // rows 0..63
    const unsigned short* pa1 = A + (size_t)(m0 + 64 + r0) * lda + c0;  // rows 64..127
    const unsigned short* pw  = W + (size_t)(n0 + r0) * ldw + c0;       // rows 0..63

    const int wm = wave & 1, wn = wave >> 1;
    const int fr = lane & 15;
    const int fk = (lane >> 4) * 8;

    stage_tiles(pa0, pa1, pw, 0, As0, Bs0, wave);   // prologue -> buf0

    for (int k0 = 0; k0 < Kloop; k0 += 128) {
        __syncthreads();                             // drains buf0's loads
        if (k0 + 64 < Kloop)
            stage_tiles(pa0, pa1, pw, k0 + 64, As1, Bs1, wave);   // prefetch buf1
        compute_tiles(As0, Bs0, acc, wm, wn, fr, fk);             // compute buf0

        __syncthreads();                             // drains buf1's loads
        if (k0 + 128 < Kloop)
            stage_tiles(pa0, pa1, pw, k0 + 128, As0, Bs0, wave);  // prefetch buf0
        if (k0 + 64 < Kloop)
            compute_tiles(As1, Bs1, acc, wm, wn, fr, fk);         // compute buf1
    }
}

// ---------------------------------------------------------------------------
// Fused input GEMM: col tiles (64-wide): 0..7 q | 8..15 k | 16..23 v |
// 24..27 off1(W_hi, x_hi) | 28..31 off2(W_lo, x_hi) | 32..35 off3(W_hi, x_lo).
// grid (36, 64).
__global__ __launch_bounds__(256, 3) void gemm_fused(
    const unsigned short* __restrict__ x_hi,
    const unsigned short* __restrict__ x_lo,
    const unsigned short* __restrict__ wall,
    const float* __restrict__ bq,
    const float* __restrict__ bkv,
    const float* __restrict__ boff,
    unsigned short* __restrict__ q_bf,
    unsigned short* __restrict__ k_bf,
    unsigned short* __restrict__ v_bf,
    float* __restrict__ off1,
    float* __restrict__ off2,
    float* __restrict__ off3) {
    __shared__ short As0[8192], As1[8192];  // 2 bufs x 2 chunks x [128][32]
    __shared__ short Bs0[4096], Bs1[4096];  // 2 bufs x 2 chunks x [64][32]
    const int t = threadIdx.x;
    const int wave = t >> 6, lane = t & 63;
    const int m0 = blockIdx.y * 128;
    const int n0 = blockIdx.x * 64;

    // x_lo pairs with the W_hi-dup segment (n >= 2048), i.e. col tiles 32..35.
    const unsigned short* A = (blockIdx.x >= 32) ? x_lo : x_hi;

    f32x4 acc[4][2] = {};
    gemm_seg_db(A, wall, m0, n0, 512, 512, 512, As0, As1, Bs0, Bs1, acc, wave, lane);

    const int wm = wave & 1, wn = wave >> 1;
    const int ecol = lane & 15;
    const int erow = (lane >> 4) * 4;
#pragma unroll
    for (int i = 0; i < 4; ++i) {
#pragma unroll
        for (int j = 0; j < 2; ++j) {
            const int n = n0 + wn * 32 + j * 16 + ecol;
#pragma unroll
            for (int r = 0; r < 4; ++r) {
                const int m = m0 + wm * 64 + i * 16 + erow + r;
                const float v = acc[i][j][r];
                if (n < 512) {
                    q_bf[(size_t)m * 512 + n] = f2b((v + bq[n]) * 0.125f);
                } else if (n < 1024) {
                    k_bf[(size_t)m * 512 + (n - 512)] = f2b(v + bkv[n - 512]);
                } else if (n < 1536) {
                    v_bf[(size_t)m * 512 + (n - 1024)] = f2b(v + bkv[n - 512]);
                } else if (n < 1792) {
                    const int c = n - 1536;
                    if (c < 144) off1[(size_t)m * 144 + c] = v + boff[c];
                } else if (n < 2048) {
                    const int c = n - 1792;
                    if (c < 144) off2[(size_t)m * 144 + c] = v;
                } else {
                    const int c = n - 2048;
                    if (c < 144) off3[(size_t)m * 144 + c] = v;
                }
            }
        }
    }
}

// ---------------------------------------------------------------------------
// Out-projection GEMM: plain, fp32 store + bias. grid (8, 64).
__global__ __launch_bounds__(256, 3) void gemm_out(
    const unsigned short* __restrict__ A,
    const unsigned short* __restrict__ W,
    const float* __restrict__ bias,
    float* __restrict__ out) {
    __shared__ short As0[8192], As1[8192];
    __shared__ short Bs0[4096], Bs1[4096];
    const int t = threadIdx.x;
    const int wave = t >> 6, lane = t & 63;
    const int m0 = blockIdx.y * 128;
    const int n0 = blockIdx.x * 64;

    f32x4 acc[4][2] = {};
    gemm_seg_db(A, W, m0, n0, 512, 512, 512, As0, As1, Bs0, Bs1, acc, wave, lane);

    const int wm = wave & 1, wn = wave >> 1;
    const int ecol = lane & 15;
    const int erow = (lane >> 4) * 4;
#pragma unroll
    for (int i = 0; i < 4; ++i) {
#pragma unroll
        for (int j = 0; j < 2; ++j) {
            const int n = n0 + wn * 32 + j * 16 + ecol;
            const float bb = bias[n];
#pragma unroll
            for (int r = 0; r < 4; ++r) {
                const int m = m0 + wm * 64 + i * 16 + erow + r;
                out[(size_t)m * 512 + n] = acc[i][j][r] + bb;
            }
        }
    }
}

// ---------------------------------------------------------------------------
// Sampling + attention, with inlined parameter computation.
// One wave = 4 consecutive tokens of one (b, head); 16 lanes per token, lane j
// covers channels 4j..4j+3 via one uint2 from each of the k and v planes.
// Lanes 0..35 first compute the wave's 4x9 sampling params (sum 3 offset-GEMM
// parts, tanh*4, bilinear weights + clamped row offsets) into LDS.
__global__ __launch_bounds__(256) void attn_sample(const unsigned short* __restrict__ q_bf,
                                                   const float* __restrict__ off1,
                                                   const float* __restrict__ off2,
                                                   const float* __restrict__ off3,
                                                   const unsigned short* __restrict__ k_bf,
                                                   const unsigned short* __restrict__ v_bf,
                                                   unsigned short* __restrict__ a_bf) {
    __shared__ float4 pw_s[4][36];
    __shared__ int4   po_s[4][36];

    const int lane = threadIdx.x & 63;
    const int wave = threadIdx.x >> 6;
    const int quarter = lane >> 4;
    const int j    = lane & 15;
    const int wid  = blockIdx.x * 4 + wave;  // [0, 16384)
    const int b    = wid >> 13;
    const int hh   = (wid >> 10) & 7;
    const int nq   = wid & 1023;
    const int n    = nq * 4 + quarter;

    // ---- parameter computation: lane l < 36 handles (qt = l/9, p = l%9) ----
    if (lane < 36) {
        const int qt = lane / 9;
        const int p  = lane - qt * 9;
        const int tn = nq * 4 + qt;
        const size_t tokq = (size_t)b * N_ + tn;
        const size_t oidx = tokq * 144 + hh * 18 + 2 * p;
        const float2 a1 = *reinterpret_cast<const float2*>(off1 + oidx);
        const float2 a2 = *reinterpret_cast<const float2*>(off2 + oidx);
        const float2 a3 = *reinterpret_cast<const float2*>(off3 + oidx);
        const float dx = tanhf(a1.x + a2.x + a3.x) * 4.0f;
        const float dy = tanhf(a1.y + a2.y + a3.y) * 4.0f;
        const float sx = (float)(tn & (GW_ - 1)) + dx;
        const float sy = (float)(tn >> 8) + dy;
        const float x0f = floorf(sx), y0f = floorf(sy);
        const int x0 = (int)x0f, y0 = (int)y0f;
        const float wx1 = sx - x0f, wy1 = sy - y0f;
        const float wx0 = 1.0f - wx1, wy0 = 1.0f - wy1;

        float4 w;
        int4 ro;
        {
            const int xi = x0, yi = y0;
            const bool v = (xi >= 0) & (xi < GW_) & (yi >= 0) & (yi < GH_);
            w.x = v ? wx0 * wy0 : 0.0f;
            const int xc = xi < 0 ? 0 : (xi > 255 ? 255 : xi);
            const int yc = yi < 0 ? 0 : (yi > 15 ? 15 : yi);
            ro.x = (yc * GW_ + xc) * 512 + hh * 64;
        }
        {
            const int xi = x0 + 1, yi = y0;
            const bool v = (xi >= 0) & (xi < GW_) & (yi >= 0) & (yi < GH_);
            w.y = v ? wx1 * wy0 : 0.0f;
            const int xc = xi < 0 ? 0 : (xi > 255 ? 255 : xi);
            const int yc = yi < 0 ? 0 : (yi > 15 ? 15 : yi);
            ro.y = (yc * GW_ + xc) * 512 + hh * 64;
        }
        {
            const int xi = x0, yi = y0 + 1;
            const bool v = (xi >= 0) & (xi < GW_) & (yi >= 0) & (yi < GH_);
            w.z = v ? wx0 * wy1 : 0.0f;
            const int xc = xi < 0 ? 0 : (xi > 255 ? 255 : xi);
            const int yc = yi < 0 ? 0 : (yi > 15 ? 15 : yi);
            ro.z = (yc * GW_ + xc) * 512 + hh * 64;
        }
        {
            const int xi = x0 + 1, yi = y0 + 1;
            const bool v = (xi >= 0) & (xi < GW_) & (yi >= 0) & (yi < GH_);
            w.w = v ? wx1 * wy1 : 0.0f;
            const int xc = xi < 0 ? 0 : (xi > 255 ? 255 : xi);
            const int yc = yi < 0 ? 0 : (yi > 15 ? 15 : yi);
            ro.w = (yc * GW_ + xc) * 512 + hh * 64;
        }
        pw_s[wave][lane] = w;
        po_s[wave][lane] = ro;
    }
    __syncthreads();

    // ---- sampling + attention ----
    const size_t tok = (size_t)b * N_ + n;
    const uint2 qp = *reinterpret_cast<const uint2*>(
        q_bf + tok * 512 + hh * 64 + 4 * j);
    const float q0 = b2f_lo(qp.x), q1 = b2f_hi(qp.x);
    const float q2 = b2f_lo(qp.y), q3 = b2f_hi(qp.y);

    const unsigned short* kbase = k_bf + (size_t)b * (N_ * 512) + 4 * j;
    const unsigned short* vbase = v_bf + (size_t)b * (N_ * 512) + 4 * j;
    const int ebase = quarter * 9;

    float lg[9], s0[9], s1[9], s2[9], s3[9];
    float mx = -1e30f;

#pragma unroll
    for (int p = 0; p < P_; ++p) {
        const float4 w = pw_s[wave][ebase + p];
        const int4 ro = po_s[wave][ebase + p];
        float k0 = 0.f, k1 = 0.f, k2 = 0.f, k3 = 0.f;
        float v0 = 0.f, v1 = 0.f, v2 = 0.f, v3 = 0.f;
#pragma unroll
        for (int c = 0; c < 4; ++c) {
            const int r = (c == 0) ? ro.x : (c == 1) ? ro.y : (c == 2) ? ro.z : ro.w;
            const float wgt = (c == 0) ? w.x : (c == 1) ? w.y : (c == 2) ? w.z : w.w;
            const uint2 ku = *reinterpret_cast<const uint2*>(kbase + r);
            const uint2 vu = *reinterpret_cast<const uint2*>(vbase + r);
            k0 = fmaf(wgt, b2f_lo(ku.x), k0); k1 = fmaf(wgt, b2f_hi(ku.x), k1);
            k2 = fmaf(wgt, b2f_lo(ku.y), k2); k3 = fmaf(wgt, b2f_hi(ku.y), k3);
            v0 = fmaf(wgt, b2f_lo(vu.x), v0); v1 = fmaf(wgt, b2f_hi(vu.x), v1);
            v2 = fmaf(wgt, b2f_lo(vu.y), v2); v3 = fmaf(wgt, b2f_hi(vu.y), v3);
        }
        float ts = fmaf(q0, k0, fmaf(q1, k1, fmaf(q2, k2, q3 * k3)));
#pragma unroll
        for (int s = 8; s > 0; s >>= 1) ts += __shfl_xor(ts, s, 64);  // 16-lane group
        lg[p] = ts;
        s0[p] = v0; s1[p] = v1; s2[p] = v2; s3[p] = v3;
        mx = fmaxf(mx, lg[p]);
    }

    float ssum = 0.f, o0 = 0.f, o1 = 0.f, o2 = 0.f, o3 = 0.f;
#pragma unroll
    for (int p = 0; p < P_; ++p) {
        const float e = __expf(lg[p] - mx);
        ssum += e;
        o0 = fmaf(e, s0[p], o0);
        o1 = fmaf(e, s1[p], o1);
        o2 = fmaf(e, s2[p], o2);
        o3 = fmaf(e, s3[p], o3);
    }
    const float rs = 1.0f / ssum;
    uint2 pack;
    pack.x = (unsigned int)f2b(o0 * rs) | ((unsigned int)f2b(o1 * rs) << 16);
    pack.y = (unsigned int)f2b(o2 * rs) | ((unsigned int)f2b(o3 * rs) << 16);
    *reinterpret_cast<uint2*>(a_bf + tok * 512 + hh * 64 + 4 * j) = pack;
}

// ---------------------------------------------------------------------------
extern "C" void kernel_launch(void* const* d_in, const int* in_sizes, int n_in,
                              void* d_out, int out_size, void* d_ws, size_t ws_size,
                              hipStream_t stream) {
    const float* x    = (const float*)d_in[0];
    const float* bq   = (const float*)d_in[2];
    const float* Woff = (const float*)d_in[3];
    const float* boff = (const float*)d_in[4];
    const float* bkv  = (const float*)d_in[6];
    const float* bo   = (const float*)d_in[8];
    float* out = (float*)d_out;

    // Workspace layout (~57 MB)
    char* ws = (char*)d_ws;
    unsigned short* q_bf    = (unsigned short*)ws; ws += (size_t)M_ * 512 * 2;    // 8 MB
    unsigned short* k_bf    = (unsigned short*)ws; ws += (size_t)M_ * 512 * 2;    // 8 MB
    unsigned short* v_bf    = (unsigned short*)ws; ws += (size_t)M_ * 512 * 2;    // 8 MB
    float*          off1    = (float*)ws;          ws += (size_t)M_ * 144 * 4;    // 4.7 MB
    float*          off2    = (float*)ws;          ws += (size_t)M_ * 144 * 4;    // 4.7 MB
    float*          off3    = (float*)ws;          ws += (size_t)M_ * 144 * 4;    // 4.7 MB
    unsigned short* xlo_abf = (unsigned short*)ws; ws += (size_t)M_ * 512 * 2;    // 8 MB (x_lo, then a_bf)
    unsigned short* x_hi    = (unsigned short*)ws; ws += (size_t)M_ * 512 * 2;    // 8 MB
    unsigned short* wall    = (unsigned short*)ws; ws += (size_t)2304 * 512 * 2;  // 2.4 MB
    unsigned short* wob     = (unsigned short*)ws; ws += (size_t)512 * 512 * 2;   // 0.5 MB

    const dim3 blk(256);

    // 0) casts (x -> hi/lo, weight wall, wo)
    cast_multi<<<dim3(5360), blk, 0, stream>>>(
        x, (const float*)d_in[1], (const float*)d_in[5], (const float*)d_in[7], Woff,
        x_hi, xlo_abf, wall, wob);

    // 1) fused input GEMM: q + k + v + 3 offset segments (2304 blocks, dbuf)
    gemm_fused<<<dim3(36, M_ / 128), blk, 0, stream>>>(
        x_hi, xlo_abf, wall, bq, bkv, boff, q_bf, k_bf, v_bf, off1, off2, off3);

    // 2) sampling + attention with fused param prep -> a_bf (aliases x_lo)
    attn_sample<<<dim3((B_ * H_ * N_) / 16), blk, 0, stream>>>(
        q_bf, off1, off2, off3, k_bf, v_bf, xlo_abf);

    // 3) out = attn @ Wo^T + bo (plain fp32 store, dbuf)
    gemm_out<<<dim3(8, M_ / 128), blk, 0, stream>>>(xlo_abf, wob, bo, out);
}

// Round 11
// 173.208 us; speedup vs baseline: 1.0837x; 1.0837x over previous
//
#include <hip/hip_runtime.h>
#include <hip/hip_bf16.h>

// Problem constants (fixed by the reference module)
static constexpr int B_  = 2;
static constexpr int N_  = 4096;
static constexpr int D_  = 512;
static constexpr int H_  = 8;
static constexpr int P_  = 9;
static constexpr int GH_ = 16;   // grid h
static constexpr int GW_ = 256;  // grid w
static constexpr int M_  = B_ * N_;  // 8192 tokens

typedef __attribute__((ext_vector_type(8))) short bf16x8;
typedef __attribute__((ext_vector_type(4))) float f32x4;

__device__ __forceinline__ unsigned short f2b(float f) {
    __hip_bfloat16 h = __float2bfloat16(f);  // round-to-nearest
    return *reinterpret_cast<unsigned short*>(&h);
}
__device__ __forceinline__ float b2f(unsigned short u) {
    return __uint_as_float(((unsigned int)u) << 16);
}
__device__ __forceinline__ float b2f_lo(unsigned int u) { return __uint_as_float(u << 16); }
__device__ __forceinline__ float b2f_hi(unsigned int u) { return __uint_as_float(u & 0xffff0000u); }

// ---------------------------------------------------------------------------
// Cast fp32 -> bf16 and build the fused weight wall (2304 rows x 512):
//   rows 0..511 Wq | 512..1535 Wkv (ROW-PERMUTED to kv-interleaved layout) |
//   1536..1679 Woff_hi (pad->1791) | 1792..1935 Woff_lo (pad->2047) |
//   2048..2191 Woff_hi dup (pad->2303)
// kv-interleaved column c (in [0,1024)): head h=c>>7, w=c&127, g=w>>3, s=w&7;
//   s<4 -> k channel h*64+4g+s ; s>=4 -> v channel h*64+4g+(s-4).
// Also emits the matching permuted bias bkv_p[1024].
__global__ __launch_bounds__(256) void cast_multi(
    const float* __restrict__ x,   const float* __restrict__ wq,
    const float* __restrict__ wkv, const float* __restrict__ wo,
    const float* __restrict__ woff, const float* __restrict__ bkv,
    unsigned short* __restrict__ x_hi, unsigned short* __restrict__ x_lo,
    unsigned short* __restrict__ wall, unsigned short* __restrict__ wob,
    float* __restrict__ bkv_p) {
    int g = blockIdx.x * 256 + threadIdx.x;

    if (g < 1048576) {  // x -> hi + lo
        float4 v = reinterpret_cast<const float4*>(x)[g];
        ushort4 hi, lo;
        hi.x = f2b(v.x); hi.y = f2b(v.y); hi.z = f2b(v.z); hi.w = f2b(v.w);
        lo.x = f2b(v.x - b2f(hi.x)); lo.y = f2b(v.y - b2f(hi.y));
        lo.z = f2b(v.z - b2f(hi.z)); lo.w = f2b(v.w - b2f(hi.w));
        reinterpret_cast<ushort4*>(x_hi)[g] = hi;
        reinterpret_cast<ushort4*>(x_lo)[g] = lo;
        return;
    }
    g -= 1048576;
    if (g < 65536) {  // Wq -> wall rows 0..511
        float4 v = reinterpret_cast<const float4*>(wq)[g];
        ushort4 o; o.x = f2b(v.x); o.y = f2b(v.y); o.z = f2b(v.z); o.w = f2b(v.w);
        reinterpret_cast<ushort4*>(wall)[g] = o;
        return;
    }
    g -= 65536;
    if (g < 131072) {  // Wkv -> wall rows 512..1535, row-permuted
        const int r  = g >> 7;     // source row in Wkv (0..1023)
        const int c4 = g & 127;    // float4 index along K
        int pr;
        if (r < 512) {             // k row: channel h*64+c
            const int h = r >> 6, c = r & 63;
            pr = h * 128 + ((c >> 2) << 3) + (c & 3);
        } else {                   // v row
            const int r2 = r - 512;
            const int h = r2 >> 6, c = r2 & 63;
            pr = h * 128 + ((c >> 2) << 3) + 4 + (c & 3);
        }
        float4 v = reinterpret_cast<const float4*>(wkv)[g];
        ushort4 o; o.x = f2b(v.x); o.y = f2b(v.y); o.z = f2b(v.z); o.w = f2b(v.w);
        reinterpret_cast<ushort4*>(wall)[65536 + pr * 128 + c4] = o;
        return;
    }
    g -= 131072;
    if (g < 65536) {  // Wo -> wob
        float4 v = reinterpret_cast<const float4*>(wo)[g];
        ushort4 o; o.x = f2b(v.x); o.y = f2b(v.y); o.z = f2b(v.z); o.w = f2b(v.w);
        reinterpret_cast<ushort4*>(wob)[g] = o;
        return;
    }
    g -= 65536;
    if (g < 18432) {  // Woff rows 0..143 -> wall hi (1536), lo (1792), hi-dup (2048)
        float4 v = reinterpret_cast<const float4*>(woff)[g];
        ushort4 hi, lo;
        hi.x = f2b(v.x); hi.y = f2b(v.y); hi.z = f2b(v.z); hi.w = f2b(v.w);
        lo.x = f2b(v.x - b2f(hi.x)); lo.y = f2b(v.y - b2f(hi.y));
        lo.z = f2b(v.z - b2f(hi.z)); lo.w = f2b(v.w - b2f(hi.w));
        reinterpret_cast<ushort4*>(wall)[196608 + g] = hi;
        reinterpret_cast<ushort4*>(wall)[229376 + g] = lo;
        reinterpret_cast<ushort4*>(wall)[262144 + g] = hi;
        return;
    }
    g -= 18432;
    if (g < 43008) {  // zero pads: rows 1680..1791 / 1936..2047 / 2192..2303
        const int which = g / 14336;
        const int idx   = g - which * 14336;
        ushort4 z = {0, 0, 0, 0};
        reinterpret_cast<ushort4*>(wall)[215040 + which * 32768 + idx] = z;
        return;
    }
    g -= 43008;
    // permuted kv bias: g in [0,256), 4 channels each
#pragma unroll
    for (int t = 0; t < 4; ++t) {
        const int c = g * 4 + t;             // interleaved channel [0,1024)
        const int h = c >> 7, w = c & 127, gr = w >> 3, s = w & 7;
        const int orig = (s < 4) ? (h * 64 + gr * 4 + s)
                                 : (512 + h * 64 + gr * 4 + (s - 4));
        bkv_p[c] = bkv[orig];
    }
}

// ---------------------------------------------------------------------------
// MFMA K-loop (R9 engine — best measured). Tile 128(M) x 64(N), BK=64
// (two 32-chunks per barrier pair -> 16 MFMA/wave/iter), LDS 24 KB.
// 4 waves: wm=wave&1, wn=wave>>1. Chunk t: A at As + t*4096 shorts
// (row-major [128][32]), B at Bs + t*2048.
__device__ __forceinline__ void gemm_seg(const unsigned short* __restrict__ A,
                                         const unsigned short* __restrict__ W,
                                         int m0, int n0, int Kloop, int lda, int ldw,
                                         short* As, short* Bs,
                                         f32x4 (&acc)[4][2], int wave, int lane) {
    const int gi = wave * 64 + lane;        // [0,256)
    const int r0 = gi >> 2, c0 = (gi & 3) * 8;

    const unsigned short* pa0 = A + (size_t)(m0 + r0) * lda + c0;       // rows 0..63
    const unsigned short* pa1 = A + (size_t)(m0 + 64 + r0) * lda + c0;  // rows 64..127
    const unsigned short* pw  = W + (size_t)(n0 + r0) * ldw + c0;       // rows 0..63

    const int wm = wave & 1, wn = wave >> 1;
    const int fr = lane & 15;
    const int fk = (lane >> 4) * 8;

    for (int k0 = 0; k0 < Kloop; k0 += 64) {
#pragma unroll
        for (int t = 0; t < 2; ++t) {
            __builtin_amdgcn_global_load_lds(
                (const __attribute__((address_space(1))) void*)(pa0 + k0 + t * 32),
                (__attribute__((address_space(3))) void*)(As + t * 4096 + wave * 512),
                16, 0, 0);
            __builtin_amdgcn_global_load_lds(
                (const __attribute__((address_space(1))) void*)(pa1 + k0 + t * 32),
                (__attribute__((address_space(3))) void*)(As + t * 4096 + 2048 + wave * 512),
                16, 0, 0);
            __builtin_amdgcn_global_load_lds(
                (const __attribute__((address_space(1))) void*)(pw + k0 + t * 32),
                (__attribute__((address_space(3))) void*)(Bs + t * 2048 + wave * 512),
                16, 0, 0);
        }
        __syncthreads();

#pragma unroll
        for (int t = 0; t < 2; ++t) {
            bf16x8 af[4], bf[2];
#pragma unroll
            for (int i = 0; i < 4; ++i)
                af[i] = *reinterpret_cast<const bf16x8*>(
                    &As[t * 4096 + (wm * 64 + i * 16 + fr) * 32 + fk]);
#pragma unroll
            for (int j = 0; j < 2; ++j)
                bf[j] = *reinterpret_cast<const bf16x8*>(
                    &Bs[t * 2048 + (wn * 32 + j * 16 + fr) * 32 + fk]);
#pragma unroll
            for (int i = 0; i < 4; ++i)
#pragma unroll
                for (int j = 0; j < 2; ++j)
                    acc[i][j] = __builtin_amdgcn_mfma_f32_16x16x32_bf16(
                        af[i], bf[j], acc[i][j], 0, 0, 0);
        }
        __syncthreads();
    }
}

// ---------------------------------------------------------------------------
// Fused input GEMM: col tiles (64-wide): 0..7 q | 8..23 kv-interleaved |
// 24..27 off1(W_hi, x_hi) | 28..31 off2(W_lo, x_hi) | 32..35 off3(W_hi, x_lo).
// grid (36, 64).
__global__ __launch_bounds__(256, 3) void gemm_fused(
    const unsigned short* __restrict__ x_hi,
    const unsigned short* __restrict__ x_lo,
    const unsigned short* __restrict__ wall,
    const float* __restrict__ bq,
    const float* __restrict__ bkv_p,
    const float* __restrict__ boff,
    unsigned short* __restrict__ q_bf,
    unsigned short* __restrict__ kv,
    float* __restrict__ off1,
    float* __restrict__ off2,
    float* __restrict__ off3) {
    __shared__ short As[8192];  // 2 chunks x [128][32]
    __shared__ short Bs[4096];  // 2 chunks x [64][32]
    const int t = threadIdx.x;
    const int wave = t >> 6, lane = t & 63;
    const int m0 = blockIdx.y * 128;
    const int n0 = blockIdx.x * 64;

    // x_lo pairs with the W_hi-dup segment (n >= 2048), i.e. col tiles 32..35.
    const unsigned short* A = (blockIdx.x >= 32) ? x_lo : x_hi;

    f32x4 acc[4][2] = {};
    gemm_seg(A, wall, m0, n0, 512, 512, 512, As, Bs, acc, wave, lane);

    const int wm = wave & 1, wn = wave >> 1;
    const int ecol = lane & 15;
    const int erow = (lane >> 4) * 4;
#pragma unroll
    for (int i = 0; i < 4; ++i) {
#pragma unroll
        for (int j = 0; j < 2; ++j) {
            const int n = n0 + wn * 32 + j * 16 + ecol;
#pragma unroll
            for (int r = 0; r < 4; ++r) {
                const int m = m0 + wm * 64 + i * 16 + erow + r;
                const float v = acc[i][j][r];
                if (n < 512) {
                    q_bf[(size_t)m * 512 + n] = f2b((v + bq[n]) * 0.125f);
                } else if (n < 1536) {
                    kv[(size_t)m * 1024 + (n - 512)] = f2b(v + bkv_p[n - 512]);
                } else if (n < 1792) {
                    const int c = n - 1536;
                    if (c < 144) off1[(size_t)m * 144 + c] = v + boff[c];
                } else if (n < 2048) {
                    const int c = n - 1792;
                    if (c < 144) off2[(size_t)m * 144 + c] = v;
                } else {
                    const int c = n - 2048;
                    if (c < 144) off3[(size_t)m * 144 + c] = v;
                }
            }
        }
    }
}

// ---------------------------------------------------------------------------
// Out-projection GEMM: plain, fp32 store + bias. grid (8, 64).
__global__ __launch_bounds__(256, 3) void gemm_out(
    const unsigned short* __restrict__ A,
    const unsigned short* __restrict__ W,
    const float* __restrict__ bias,
    float* __restrict__ out) {
    __shared__ short As[8192];
    __shared__ short Bs[4096];
    const int t = threadIdx.x;
    const int wave = t >> 6, lane = t & 63;
    const int m0 = blockIdx.y * 128;
    const int n0 = blockIdx.x * 64;

    f32x4 acc[4][2] = {};
    gemm_seg(A, W, m0, n0, 512, 512, 512, As, Bs, acc, wave, lane);

    const int wm = wave & 1, wn = wave >> 1;
    const int ecol = lane & 15;
    const int erow = (lane >> 4) * 4;
#pragma unroll
    for (int i = 0; i < 4; ++i) {
#pragma unroll
        for (int j = 0; j < 2; ++j) {
            const int n = n0 + wn * 32 + j * 16 + ecol;
            const float bb = bias[n];
#pragma unroll
            for (int r = 0; r < 4; ++r) {
                const int m = m0 + wm * 64 + i * 16 + erow + r;
                out[(size_t)m * 512 + n] = acc[i][j][r] + bb;
            }
        }
    }
}

// ---------------------------------------------------------------------------
// Sampling + attention, with inlined parameter computation.
// One wave = 4 consecutive tokens of one (b, head); 16 lanes per token, lane j
// covers channels 4j..4j+3 via ONE uint4 per corner from the kv-interleaved
// plane ([pixel][head][group j][k0..3 v0..3]). Lanes 0..35 first compute the
// wave's 4x9 sampling params into LDS.
__global__ __launch_bounds__(256) void attn_sample(const unsigned short* __restrict__ q_bf,
                                                   const float* __restrict__ off1,
                                                   const float* __restrict__ off2,
                                                   const float* __restrict__ off3,
                                                   const unsigned short* __restrict__ kv,
                                                   unsigned short* __restrict__ a_bf) {
    __shared__ float4 pw_s[4][36];
    __shared__ int4   po_s[4][36];

    const int lane = threadIdx.x & 63;
    const int wave = threadIdx.x >> 6;
    const int quarter = lane >> 4;
    const int j    = lane & 15;
    const int wid  = blockIdx.x * 4 + wave;  // [0, 16384)
    const int b    = wid >> 13;
    const int hh   = (wid >> 10) & 7;
    const int nq   = wid & 1023;
    const int n    = nq * 4 + quarter;

    // ---- parameter computation: lane l < 36 handles (qt = l/9, p = l%9) ----
    if (lane < 36) {
        const int qt = lane / 9;
        const int p  = lane - qt * 9;
        const int tn = nq * 4 + qt;
        const size_t tokq = (size_t)b * N_ + tn;
        const size_t oidx = tokq * 144 + hh * 18 + 2 * p;
        const float2 a1 = *reinterpret_cast<const float2*>(off1 + oidx);
        const float2 a2 = *reinterpret_cast<const float2*>(off2 + oidx);
        const float2 a3 = *reinterpret_cast<const float2*>(off3 + oidx);
        const float dx = tanhf(a1.x + a2.x + a3.x) * 4.0f;
        const float dy = tanhf(a1.y + a2.y + a3.y) * 4.0f;
        const float sx = (float)(tn & (GW_ - 1)) + dx;
        const float sy = (float)(tn >> 8) + dy;
        const float x0f = floorf(sx), y0f = floorf(sy);
        const int x0 = (int)x0f, y0 = (int)y0f;
        const float wx1 = sx - x0f, wy1 = sy - y0f;
        const float wx0 = 1.0f - wx1, wy0 = 1.0f - wy1;

        float4 w;
        int4 ro;
        {
            const int xi = x0, yi = y0;
            const bool v = (xi >= 0) & (xi < GW_) & (yi >= 0) & (yi < GH_);
            w.x = v ? wx0 * wy0 : 0.0f;
            const int xc = xi < 0 ? 0 : (xi > 255 ? 255 : xi);
            const int yc = yi < 0 ? 0 : (yi > 15 ? 15 : yi);
            ro.x = (yc * GW_ + xc) * 1024 + hh * 128;
        }
        {
            const int xi = x0 + 1, yi = y0;
            const bool v = (xi >= 0) & (xi < GW_) & (yi >= 0) & (yi < GH_);
            w.y = v ? wx1 * wy0 : 0.0f;
            const int xc = xi < 0 ? 0 : (xi > 255 ? 255 : xi);
            const int yc = yi < 0 ? 0 : (yi > 15 ? 15 : yi);
            ro.y = (yc * GW_ + xc) * 1024 + hh * 128;
        }
        {
            const int xi = x0, yi = y0 + 1;
            const bool v = (xi >= 0) & (xi < GW_) & (yi >= 0) & (yi < GH_);
            w.z = v ? wx0 * wy1 : 0.0f;
            const int xc = xi < 0 ? 0 : (xi > 255 ? 255 : xi);
            const int yc = yi < 0 ? 0 : (yi > 15 ? 15 : yi);
            ro.z = (yc * GW_ + xc) * 1024 + hh * 128;
        }
        {
            const int xi = x0 + 1, yi = y0 + 1;
            const bool v = (xi >= 0) & (xi < GW_) & (yi >= 0) & (yi < GH_);
            w.w = v ? wx1 * wy1 : 0.0f;
            const int xc = xi < 0 ? 0 : (xi > 255 ? 255 : xi);
            const int yc = yi < 0 ? 0 : (yi > 15 ? 15 : yi);
            ro.w = (yc * GW_ + xc) * 1024 + hh * 128;
        }
        pw_s[wave][lane] = w;
        po_s[wave][lane] = ro;
    }
    __syncthreads();

    // ---- sampling + attention ----
    const size_t tok = (size_t)b * N_ + n;
    const uint2 qp = *reinterpret_cast<const uint2*>(
        q_bf + tok * 512 + hh * 64 + 4 * j);
    const float q0 = b2f_lo(qp.x), q1 = b2f_hi(qp.x);
    const float q2 = b2f_lo(qp.y), q3 = b2f_hi(qp.y);

    const unsigned short* kvbase = kv + (size_t)b * (N_ * 1024) + 8 * j;
    const int ebase = quarter * 9;

    float lg[9], s0[9], s1[9], s2[9], s3[9];
    float mx = -1e30f;

#pragma unroll
    for (int p = 0; p < P_; ++p) {
        const float4 w = pw_s[wave][ebase + p];
        const int4 ro = po_s[wave][ebase + p];
        float k0 = 0.f, k1 = 0.f, k2 = 0.f, k3 = 0.f;
        float v0 = 0.f, v1 = 0.f, v2 = 0.f, v3 = 0.f;
#pragma unroll
        for (int c = 0; c < 4; ++c) {
            const int r = (c == 0) ? ro.x : (c == 1) ? ro.y : (c == 2) ? ro.z : ro.w;
            const float wgt = (c == 0) ? w.x : (c == 1) ? w.y : (c == 2) ? w.z : w.w;
            const uint4 u = *reinterpret_cast<const uint4*>(kvbase + r);
            k0 = fmaf(wgt, b2f_lo(u.x), k0); k1 = fmaf(wgt, b2f_hi(u.x), k1);
            k2 = fmaf(wgt, b2f_lo(u.y), k2); k3 = fmaf(wgt, b2f_hi(u.y), k3);
            v0 = fmaf(wgt, b2f_lo(u.z), v0); v1 = fmaf(wgt, b2f_hi(u.z), v1);
            v2 = fmaf(wgt, b2f_lo(u.w), v2); v3 = fmaf(wgt, b2f_hi(u.w), v3);
        }
        float ts = fmaf(q0, k0, fmaf(q1, k1, fmaf(q2, k2, q3 * k3)));
#pragma unroll
        for (int s = 8; s > 0; s >>= 1) ts += __shfl_xor(ts, s, 64);  // 16-lane group
        lg[p] = ts;
        s0[p] = v0; s1[p] = v1; s2[p] = v2; s3[p] = v3;
        mx = fmaxf(mx, lg[p]);
    }

    float ssum = 0.f, o0 = 0.f, o1 = 0.f, o2 = 0.f, o3 = 0.f;
#pragma unroll
    for (int p = 0; p < P_; ++p) {
        const float e = __expf(lg[p] - mx);
        ssum += e;
        o0 = fmaf(e, s0[p], o0);
        o1 = fmaf(e, s1[p], o1);
        o2 = fmaf(e, s2[p], o2);
        o3 = fmaf(e, s3[p], o3);
    }
    const float rs = 1.0f / ssum;
    uint2 pack;
    pack.x = (unsigned int)f2b(o0 * rs) | ((unsigned int)f2b(o1 * rs) << 16);
    pack.y = (unsigned int)f2b(o2 * rs) | ((unsigned int)f2b(o3 * rs) << 16);
    *reinterpret_cast<uint2*>(a_bf + tok * 512 + hh * 64 + 4 * j) = pack;
}

// ---------------------------------------------------------------------------
extern "C" void kernel_launch(void* const* d_in, const int* in_sizes, int n_in,
                              void* d_out, int out_size, void* d_ws, size_t ws_size,
                              hipStream_t stream) {
    const float* x    = (const float*)d_in[0];
    const float* bq   = (const float*)d_in[2];
    const float* Woff = (const float*)d_in[3];
    const float* boff = (const float*)d_in[4];
    const float* bkv  = (const float*)d_in[6];
    const float* bo   = (const float*)d_in[8];
    float* out = (float*)d_out;

    // Workspace layout (~57 MB)
    char* ws = (char*)d_ws;
    unsigned short* q_bf    = (unsigned short*)ws; ws += (size_t)M_ * 512 * 2;     // 8 MB
    unsigned short* kv      = (unsigned short*)ws; ws += (size_t)M_ * 1024 * 2;    // 16.8 MB
    float*          off1    = (float*)ws;          ws += (size_t)M_ * 144 * 4;     // 4.7 MB
    float*          off2    = (float*)ws;          ws += (size_t)M_ * 144 * 4;     // 4.7 MB
    float*          off3    = (float*)ws;          ws += (size_t)M_ * 144 * 4;     // 4.7 MB
    unsigned short* xlo_abf = (unsigned short*)ws; ws += (size_t)M_ * 512 * 2;     // 8 MB (x_lo, then a_bf)
    unsigned short* x_hi    = (unsigned short*)ws; ws += (size_t)M_ * 512 * 2;     // 8 MB
    unsigned short* wall    = (unsigned short*)ws; ws += (size_t)2304 * 512 * 2;   // 2.4 MB
    unsigned short* wob     = (unsigned short*)ws; ws += (size_t)512 * 512 * 2;    // 0.5 MB
    float*          bkv_p   = (float*)ws;          ws += (size_t)1024 * 4;         // 4 KB

    const dim3 blk(256);

    // 0) casts (x -> hi/lo, weight wall w/ kv row permutation, wo, bias perm)
    cast_multi<<<dim3(5361), blk, 0, stream>>>(
        x, (const float*)d_in[1], (const float*)d_in[5], (const float*)d_in[7], Woff,
        bkv, x_hi, xlo_abf, wall, wob, bkv_p);

    // 1) fused input GEMM: q + interleaved kv + 3 offset segments (2304 blocks)
    gemm_fused<<<dim3(36, M_ / 128), blk, 0, stream>>>(
        x_hi, xlo_abf, wall, bq, bkv_p, boff, q_bf, kv, off1, off2, off3);

    // 2) sampling + attention with fused param prep -> a_bf (aliases x_lo)
    attn_sample<<<dim3((B_ * H_ * N_) / 16), blk, 0, stream>>>(
        q_bf, off1, off2, off3, kv, xlo_abf);

    // 3) out = attn @ Wo^T + bo (plain fp32 store)
    gemm_out<<<dim3(8, M_ / 128), blk, 0, stream>>>(xlo_abf, wob, bo, out);
}

// Round 12
// 170.521 us; speedup vs baseline: 1.1008x; 1.0158x over previous
//
#include <hip/hip_runtime.h>
#include <hip/hip_bf16.h>

// Problem constants (fixed by the reference module)
static constexpr int B_  = 2;
static constexpr int N_  = 4096;
static constexpr int D_  = 512;
static constexpr int H_  = 8;
static constexpr int P_  = 9;
static constexpr int GH_ = 16;   // grid h
static constexpr int GW_ = 256;  // grid w
static constexpr int M_  = B_ * N_;  // 8192 tokens

typedef __attribute__((ext_vector_type(8))) short bf16x8;
typedef __attribute__((ext_vector_type(4))) float f32x4;

__device__ __forceinline__ unsigned short f2b(float f) {
    __hip_bfloat16 h = __float2bfloat16(f);  // round-to-nearest
    return *reinterpret_cast<unsigned short*>(&h);
}
__device__ __forceinline__ float b2f(unsigned short u) {
    return __uint_as_float(((unsigned int)u) << 16);
}
__device__ __forceinline__ float b2f_lo(unsigned int u) { return __uint_as_float(u << 16); }
__device__ __forceinline__ float b2f_hi(unsigned int u) { return __uint_as_float(u & 0xffff0000u); }

// ---------------------------------------------------------------------------
// Cast fp32 -> bf16 and build the fused weight wall (2304 rows x 512):
//   rows 0..511 Wq | 512..1535 Wkv (ROW-PERMUTED to kv-interleaved layout) |
//   1536..1679 Woff_hi (pad->1791) | 1792..1935 Woff_lo (pad->2047) |
//   2048..2191 Woff_hi dup (pad->2303)
// kv-interleaved column c (in [0,1024)): head h=c>>7, w=c&127, g=w>>3, s=w&7;
//   s<4 -> k channel h*64+4g+s ; s>=4 -> v channel h*64+4g+(s-4).
// Also emits the matching permuted bias bkv_p[1024].
__global__ __launch_bounds__(256) void cast_multi(
    const float* __restrict__ x,   const float* __restrict__ wq,
    const float* __restrict__ wkv, const float* __restrict__ wo,
    const float* __restrict__ woff, const float* __restrict__ bkv,
    unsigned short* __restrict__ x_hi, unsigned short* __restrict__ x_lo,
    unsigned short* __restrict__ wall, unsigned short* __restrict__ wob,
    float* __restrict__ bkv_p) {
    int g = blockIdx.x * 256 + threadIdx.x;

    if (g < 1048576) {  // x -> hi + lo
        float4 v = reinterpret_cast<const float4*>(x)[g];
        ushort4 hi, lo;
        hi.x = f2b(v.x); hi.y = f2b(v.y); hi.z = f2b(v.z); hi.w = f2b(v.w);
        lo.x = f2b(v.x - b2f(hi.x)); lo.y = f2b(v.y - b2f(hi.y));
        lo.z = f2b(v.z - b2f(hi.z)); lo.w = f2b(v.w - b2f(hi.w));
        reinterpret_cast<ushort4*>(x_hi)[g] = hi;
        reinterpret_cast<ushort4*>(x_lo)[g] = lo;
        return;
    }
    g -= 1048576;
    if (g < 65536) {  // Wq -> wall rows 0..511
        float4 v = reinterpret_cast<const float4*>(wq)[g];
        ushort4 o; o.x = f2b(v.x); o.y = f2b(v.y); o.z = f2b(v.z); o.w = f2b(v.w);
        reinterpret_cast<ushort4*>(wall)[g] = o;
        return;
    }
    g -= 65536;
    if (g < 131072) {  // Wkv -> wall rows 512..1535, row-permuted
        const int r  = g >> 7;     // source row in Wkv (0..1023)
        const int c4 = g & 127;    // float4 index along K
        int pr;
        if (r < 512) {             // k row: channel h*64+c
            const int h = r >> 6, c = r & 63;
            pr = h * 128 + ((c >> 2) << 3) + (c & 3);
        } else {                   // v row
            const int r2 = r - 512;
            const int h = r2 >> 6, c = r2 & 63;
            pr = h * 128 + ((c >> 2) << 3) + 4 + (c & 3);
        }
        float4 v = reinterpret_cast<const float4*>(wkv)[g];
        ushort4 o; o.x = f2b(v.x); o.y = f2b(v.y); o.z = f2b(v.z); o.w = f2b(v.w);
        reinterpret_cast<ushort4*>(wall)[65536 + pr * 128 + c4] = o;
        return;
    }
    g -= 131072;
    if (g < 65536) {  // Wo -> wob
        float4 v = reinterpret_cast<const float4*>(wo)[g];
        ushort4 o; o.x = f2b(v.x); o.y = f2b(v.y); o.z = f2b(v.z); o.w = f2b(v.w);
        reinterpret_cast<ushort4*>(wob)[g] = o;
        return;
    }
    g -= 65536;
    if (g < 18432) {  // Woff rows 0..143 -> wall hi (1536), lo (1792), hi-dup (2048)
        float4 v = reinterpret_cast<const float4*>(woff)[g];
        ushort4 hi, lo;
        hi.x = f2b(v.x); hi.y = f2b(v.y); hi.z = f2b(v.z); hi.w = f2b(v.w);
        lo.x = f2b(v.x - b2f(hi.x)); lo.y = f2b(v.y - b2f(hi.y));
        lo.z = f2b(v.z - b2f(hi.z)); lo.w = f2b(v.w - b2f(hi.w));
        reinterpret_cast<ushort4*>(wall)[196608 + g] = hi;
        reinterpret_cast<ushort4*>(wall)[229376 + g] = lo;
        reinterpret_cast<ushort4*>(wall)[262144 + g] = hi;
        return;
    }
    g -= 18432;
    if (g < 43008) {  // zero pads: rows 1680..1791 / 1936..2047 / 2192..2303
        const int which = g / 14336;
        const int idx   = g - which * 14336;
        ushort4 z = {0, 0, 0, 0};
        reinterpret_cast<ushort4*>(wall)[215040 + which * 32768 + idx] = z;
        return;
    }
    g -= 43008;
    // permuted kv bias: g in [0,256), 4 channels each
#pragma unroll
    for (int t = 0; t < 4; ++t) {
        const int c = g * 4 + t;             // interleaved channel [0,1024)
        const int h = c >> 7, w = c & 127, gr = w >> 3, s = w & 7;
        const int orig = (s < 4) ? (h * 64 + gr * 4 + s)
                                 : (512 + h * 64 + gr * 4 + (s - 4));
        bkv_p[c] = bkv[orig];
    }
}

// ---------------------------------------------------------------------------
// MFMA K-loop (R9 engine — best measured). Tile 128(M) x 64(N), BK=64
// (two 32-chunks per barrier pair -> 16 MFMA/wave/iter), LDS 24 KB.
// 4 waves: wm=wave&1, wn=wave>>1. Chunk t: A at As + t*4096 shorts
// (row-major [128][32]), B at Bs + t*2048.
__device__ __forceinline__ void gemm_seg(const unsigned short* __restrict__ A,
                                         const unsigned short* __restrict__ W,
                                         int m0, int n0, int Kloop, int lda, int ldw,
                                         short* As, short* Bs,
                                         f32x4 (&acc)[4][2], int wave, int lane) {
    const int gi = wave * 64 + lane;        // [0,256)
    const int r0 = gi >> 2, c0 = (gi & 3) * 8;

    const unsigned short* pa0 = A + (size_t)(m0 + r0) * lda + c0;       // rows 0..63
    const unsigned short* pa1 = A + (size_t)(m0 + 64 + r0) * lda + c0;  // rows 64..127
    const unsigned short* pw  = W + (size_t)(n0 + r0) * ldw + c0;       // rows 0..63

    const int wm = wave & 1, wn = wave >> 1;
    const int fr = lane & 15;
    const int fk = (lane >> 4) * 8;

    for (int k0 = 0; k0 < Kloop; k0 += 64) {
#pragma unroll
        for (int t = 0; t < 2; ++t) {
            __builtin_amdgcn_global_load_lds(
                (const __attribute__((address_space(1))) void*)(pa0 + k0 + t * 32),
                (__attribute__((address_space(3))) void*)(As + t * 4096 + wave * 512),
                16, 0, 0);
            __builtin_amdgcn_global_load_lds(
                (const __attribute__((address_space(1))) void*)(pa1 + k0 + t * 32),
                (__attribute__((address_space(3))) void*)(As + t * 4096 + 2048 + wave * 512),
                16, 0, 0);
            __builtin_amdgcn_global_load_lds(
                (const __attribute__((address_space(1))) void*)(pw + k0 + t * 32),
                (__attribute__((address_space(3))) void*)(Bs + t * 2048 + wave * 512),
                16, 0, 0);
        }
        __syncthreads();

#pragma unroll
        for (int t = 0; t < 2; ++t) {
            bf16x8 af[4], bf[2];
#pragma unroll
            for (int i = 0; i < 4; ++i)
                af[i] = *reinterpret_cast<const bf16x8*>(
                    &As[t * 4096 + (wm * 64 + i * 16 + fr) * 32 + fk]);
#pragma unroll
            for (int j = 0; j < 2; ++j)
                bf[j] = *reinterpret_cast<const bf16x8*>(
                    &Bs[t * 2048 + (wn * 32 + j * 16 + fr) * 32 + fk]);
#pragma unroll
            for (int i = 0; i < 4; ++i)
#pragma unroll
                for (int j = 0; j < 2; ++j)
                    acc[i][j] = __builtin_amdgcn_mfma_f32_16x16x32_bf16(
                        af[i], bf[j], acc[i][j], 0, 0, 0);
        }
        __syncthreads();
    }
}

// ---------------------------------------------------------------------------
// Fused input GEMM, XCD-swizzled 1-D grid (2304 blocks).
// Work tiles: ty in [0,64) = 128-row M tile; tx in [0,36) = 64-col N tile:
//   0..7 q | 8..23 kv-interleaved | 24..27 off1(W_hi,x_hi) |
//   28..31 off2(W_lo,x_hi) | 32..35 off3(W_hi,x_lo).
// Swizzle: xcd=l&7, i=l>>3, ty=xcd+8*(i/36), tx=i%36 -> all 36 col tiles of a
// row tile dispatch to the same XCD (round-robin heuristic), A tile stays in
// that XCD's L2 (per-XCD working set ~1 MB A + 2.4 MB wall < 4 MB).
__global__ __launch_bounds__(256, 3) void gemm_fused(
    const unsigned short* __restrict__ x_hi,
    const unsigned short* __restrict__ x_lo,
    const unsigned short* __restrict__ wall,
    const float* __restrict__ bq,
    const float* __restrict__ bkv_p,
    const float* __restrict__ boff,
    unsigned short* __restrict__ q_bf,
    unsigned short* __restrict__ kv,
    float* __restrict__ off1,
    float* __restrict__ off2,
    float* __restrict__ off3) {
    __shared__ short As[8192];  // 2 chunks x [128][32]
    __shared__ short Bs[4096];  // 2 chunks x [64][32]
    const int t = threadIdx.x;
    const int wave = t >> 6, lane = t & 63;

    const int l   = blockIdx.x;
    const int xcd = l & 7;
    const int i   = l >> 3;        // [0,288)
    const int iq  = i / 36;        // [0,8)
    const int tx  = i - iq * 36;   // [0,36)
    const int ty  = xcd + 8 * iq;  // [0,64)

    const int m0 = ty * 128;
    const int n0 = tx * 64;

    // x_lo pairs with the W_hi-dup segment (n >= 2048), i.e. col tiles 32..35.
    const unsigned short* A = (tx >= 32) ? x_lo : x_hi;

    f32x4 acc[4][2] = {};
    gemm_seg(A, wall, m0, n0, 512, 512, 512, As, Bs, acc, wave, lane);

    const int wm = wave & 1, wn = wave >> 1;
    const int ecol = lane & 15;
    const int erow = (lane >> 4) * 4;
#pragma unroll
    for (int i2 = 0; i2 < 4; ++i2) {
#pragma unroll
        for (int j = 0; j < 2; ++j) {
            const int n = n0 + wn * 32 + j * 16 + ecol;
#pragma unroll
            for (int r = 0; r < 4; ++r) {
                const int m = m0 + wm * 64 + i2 * 16 + erow + r;
                const float v = acc[i2][j][r];
                if (n < 512) {
                    q_bf[(size_t)m * 512 + n] = f2b((v + bq[n]) * 0.125f);
                } else if (n < 1536) {
                    kv[(size_t)m * 1024 + (n - 512)] = f2b(v + bkv_p[n - 512]);
                } else if (n < 1792) {
                    const int c = n - 1536;
                    if (c < 144) off1[(size_t)m * 144 + c] = v + boff[c];
                } else if (n < 2048) {
                    const int c = n - 1792;
                    if (c < 144) off2[(size_t)m * 144 + c] = v;
                } else {
                    const int c = n - 2048;
                    if (c < 144) off3[(size_t)m * 144 + c] = v;
                }
            }
        }
    }
}

// ---------------------------------------------------------------------------
// Out-projection GEMM, XCD-swizzled 1-D grid (512 blocks): xcd=l&7, i=l>>3,
// ty=xcd+8*(i>>3), tx=i&7. fp32 store + bias.
__global__ __launch_bounds__(256, 3) void gemm_out(
    const unsigned short* __restrict__ A,
    const unsigned short* __restrict__ W,
    const float* __restrict__ bias,
    float* __restrict__ out) {
    __shared__ short As[8192];
    __shared__ short Bs[4096];
    const int t = threadIdx.x;
    const int wave = t >> 6, lane = t & 63;

    const int l   = blockIdx.x;
    const int xcd = l & 7;
    const int i   = l >> 3;        // [0,64)
    const int tx  = i & 7;
    const int ty  = xcd + 8 * (i >> 3);

    const int m0 = ty * 128;
    const int n0 = tx * 64;

    f32x4 acc[4][2] = {};
    gemm_seg(A, W, m0, n0, 512, 512, 512, As, Bs, acc, wave, lane);

    const int wm = wave & 1, wn = wave >> 1;
    const int ecol = lane & 15;
    const int erow = (lane >> 4) * 4;
#pragma unroll
    for (int i2 = 0; i2 < 4; ++i2) {
#pragma unroll
        for (int j = 0; j < 2; ++j) {
            const int n = n0 + wn * 32 + j * 16 + ecol;
            const float bb = bias[n];
#pragma unroll
            for (int r = 0; r < 4; ++r) {
                const int m = m0 + wm * 64 + i2 * 16 + erow + r;
                out[(size_t)m * 512 + n] = acc[i2][j][r] + bb;
            }
        }
    }
}

// ---------------------------------------------------------------------------
// Sampling + attention, with inlined parameter computation.
// XCD swizzle: bsw=(l&7)*512+(l>>3) -> each XCD owns contiguous token ranges
// (~2 (b,head) groups, kv slices ~2 MB) for L2 locality.
// One wave = 4 consecutive tokens of one (b, head); 16 lanes per token, lane j
// covers channels 4j..4j+3 via ONE uint4 per corner from the kv-interleaved
// plane. Lanes 0..35 first compute the wave's 4x9 sampling params into LDS.
__global__ __launch_bounds__(256) void attn_sample(const unsigned short* __restrict__ q_bf,
                                                   const float* __restrict__ off1,
                                                   const float* __restrict__ off2,
                                                   const float* __restrict__ off3,
                                                   const unsigned short* __restrict__ kv,
                                                   unsigned short* __restrict__ a_bf) {
    __shared__ float4 pw_s[4][36];
    __shared__ int4   po_s[4][36];

    const int lane = threadIdx.x & 63;
    const int wave = threadIdx.x >> 6;
    const int quarter = lane >> 4;
    const int j    = lane & 15;
    const int bsw  = (blockIdx.x & 7) * 512 + (blockIdx.x >> 3);  // [0,4096)
    const int wid  = bsw * 4 + wave;  // [0, 16384)
    const int b    = wid >> 13;
    const int hh   = (wid >> 10) & 7;
    const int nq   = wid & 1023;
    const int n    = nq * 4 + quarter;

    // ---- parameter computation: lane l < 36 handles (qt = l/9, p = l%9) ----
    if (lane < 36) {
        const int qt = lane / 9;
        const int p  = lane - qt * 9;
        const int tn = nq * 4 + qt;
        const size_t tokq = (size_t)b * N_ + tn;
        const size_t oidx = tokq * 144 + hh * 18 + 2 * p;
        const float2 a1 = *reinterpret_cast<const float2*>(off1 + oidx);
        const float2 a2 = *reinterpret_cast<const float2*>(off2 + oidx);
        const float2 a3 = *reinterpret_cast<const float2*>(off3 + oidx);
        const float dx = tanhf(a1.x + a2.x + a3.x) * 4.0f;
        const float dy = tanhf(a1.y + a2.y + a3.y) * 4.0f;
        const float sx = (float)(tn & (GW_ - 1)) + dx;
        const float sy = (float)(tn >> 8) + dy;
        const float x0f = floorf(sx), y0f = floorf(sy);
        const int x0 = (int)x0f, y0 = (int)y0f;
        const float wx1 = sx - x0f, wy1 = sy - y0f;
        const float wx0 = 1.0f - wx1, wy0 = 1.0f - wy1;

        float4 w;
        int4 ro;
        {
            const int xi = x0, yi = y0;
            const bool v = (xi >= 0) & (xi < GW_) & (yi >= 0) & (yi < GH_);
            w.x = v ? wx0 * wy0 : 0.0f;
            const int xc = xi < 0 ? 0 : (xi > 255 ? 255 : xi);
            const int yc = yi < 0 ? 0 : (yi > 15 ? 15 : yi);
            ro.x = (yc * GW_ + xc) * 1024 + hh * 128;
        }
        {
            const int xi = x0 + 1, yi = y0;
            const bool v = (xi >= 0) & (xi < GW_) & (yi >= 0) & (yi < GH_);
            w.y = v ? wx1 * wy0 : 0.0f;
            const int xc = xi < 0 ? 0 : (xi > 255 ? 255 : xi);
            const int yc = yi < 0 ? 0 : (yi > 15 ? 15 : yi);
            ro.y = (yc * GW_ + xc) * 1024 + hh * 128;
        }
        {
            const int xi = x0, yi = y0 + 1;
            const bool v = (xi >= 0) & (xi < GW_) & (yi >= 0) & (yi < GH_);
            w.z = v ? wx0 * wy1 : 0.0f;
            const int xc = xi < 0 ? 0 : (xi > 255 ? 255 : xi);
            const int yc = yi < 0 ? 0 : (yi > 15 ? 15 : yi);
            ro.z = (yc * GW_ + xc) * 1024 + hh * 128;
        }
        {
            const int xi = x0 + 1, yi = y0 + 1;
            const bool v = (xi >= 0) & (xi < GW_) & (yi >= 0) & (yi < GH_);
            w.w = v ? wx1 * wy1 : 0.0f;
            const int xc = xi < 0 ? 0 : (xi > 255 ? 255 : xi);
            const int yc = yi < 0 ? 0 : (yi > 15 ? 15 : yi);
            ro.w = (yc * GW_ + xc) * 1024 + hh * 128;
        }
        pw_s[wave][lane] = w;
        po_s[wave][lane] = ro;
    }
    __syncthreads();

    // ---- sampling + attention ----
    const size_t tok = (size_t)b * N_ + n;
    const uint2 qp = *reinterpret_cast<const uint2*>(
        q_bf + tok * 512 + hh * 64 + 4 * j);
    const float q0 = b2f_lo(qp.x), q1 = b2f_hi(qp.x);
    const float q2 = b2f_lo(qp.y), q3 = b2f_hi(qp.y);

    const unsigned short* kvbase = kv + (size_t)b * (N_ * 1024) + 8 * j;
    const int ebase = quarter * 9;

    float lg[9], s0[9], s1[9], s2[9], s3[9];
    float mx = -1e30f;

#pragma unroll
    for (int p = 0; p < P_; ++p) {
        const float4 w = pw_s[wave][ebase + p];
        const int4 ro = po_s[wave][ebase + p];
        float k0 = 0.f, k1 = 0.f, k2 = 0.f, k3 = 0.f;
        float v0 = 0.f, v1 = 0.f, v2 = 0.f, v3 = 0.f;
#pragma unroll
        for (int c = 0; c < 4; ++c) {
            const int r = (c == 0) ? ro.x : (c == 1) ? ro.y : (c == 2) ? ro.z : ro.w;
            const float wgt = (c == 0) ? w.x : (c == 1) ? w.y : (c == 2) ? w.z : w.w;
            const uint4 u = *reinterpret_cast<const uint4*>(kvbase + r);
            k0 = fmaf(wgt, b2f_lo(u.x), k0); k1 = fmaf(wgt, b2f_hi(u.x), k1);
            k2 = fmaf(wgt, b2f_lo(u.y), k2); k3 = fmaf(wgt, b2f_hi(u.y), k3);
            v0 = fmaf(wgt, b2f_lo(u.z), v0); v1 = fmaf(wgt, b2f_hi(u.z), v1);
            v2 = fmaf(wgt, b2f_lo(u.w), v2); v3 = fmaf(wgt, b2f_hi(u.w), v3);
        }
        float ts = fmaf(q0, k0, fmaf(q1, k1, fmaf(q2, k2, q3 * k3)));
#pragma unroll
        for (int s = 8; s > 0; s >>= 1) ts += __shfl_xor(ts, s, 64);  // 16-lane group
        lg[p] = ts;
        s0[p] = v0; s1[p] = v1; s2[p] = v2; s3[p] = v3;
        mx = fmaxf(mx, lg[p]);
    }

    float ssum = 0.f, o0 = 0.f, o1 = 0.f, o2 = 0.f, o3 = 0.f;
#pragma unroll
    for (int p = 0; p < P_; ++p) {
        const float e = __expf(lg[p] - mx);
        ssum += e;
        o0 = fmaf(e, s0[p], o0);
        o1 = fmaf(e, s1[p], o1);
        o2 = fmaf(e, s2[p], o2);
        o3 = fmaf(e, s3[p], o3);
    }
    const float rs = 1.0f / ssum;
    uint2 pack;
    pack.x = (unsigned int)f2b(o0 * rs) | ((unsigned int)f2b(o1 * rs) << 16);
    pack.y = (unsigned int)f2b(o2 * rs) | ((unsigned int)f2b(o3 * rs) << 16);
    *reinterpret_cast<uint2*>(a_bf + tok * 512 + hh * 64 + 4 * j) = pack;
}

// ---------------------------------------------------------------------------
extern "C" void kernel_launch(void* const* d_in, const int* in_sizes, int n_in,
                              void* d_out, int out_size, void* d_ws, size_t ws_size,
                              hipStream_t stream) {
    const float* x    = (const float*)d_in[0];
    const float* bq   = (const float*)d_in[2];
    const float* Woff = (const float*)d_in[3];
    const float* boff = (const float*)d_in[4];
    const float* bkv  = (const float*)d_in[6];
    const float* bo   = (const float*)d_in[8];
    float* out = (float*)d_out;

    // Workspace layout (~57 MB)
    char* ws = (char*)d_ws;
    unsigned short* q_bf    = (unsigned short*)ws; ws += (size_t)M_ * 512 * 2;     // 8 MB
    unsigned short* kv      = (unsigned short*)ws; ws += (size_t)M_ * 1024 * 2;    // 16.8 MB
    float*          off1    = (float*)ws;          ws += (size_t)M_ * 144 * 4;     // 4.7 MB
    float*          off2    = (float*)ws;          ws += (size_t)M_ * 144 * 4;     // 4.7 MB
    float*          off3    = (float*)ws;          ws += (size_t)M_ * 144 * 4;     // 4.7 MB
    unsigned short* xlo_abf = (unsigned short*)ws; ws += (size_t)M_ * 512 * 2;     // 8 MB (x_lo, then a_bf)
    unsigned short* x_hi    = (unsigned short*)ws; ws += (size_t)M_ * 512 * 2;     // 8 MB
    unsigned short* wall    = (unsigned short*)ws; ws += (size_t)2304 * 512 * 2;   // 2.4 MB
    unsigned short* wob     = (unsigned short*)ws; ws += (size_t)512 * 512 * 2;    // 0.5 MB
    float*          bkv_p   = (float*)ws;          ws += (size_t)1024 * 4;         // 4 KB

    const dim3 blk(256);

    // 0) casts (x -> hi/lo, weight wall w/ kv row permutation, wo, bias perm)
    cast_multi<<<dim3(5361), blk, 0, stream>>>(
        x, (const float*)d_in[1], (const float*)d_in[5], (const float*)d_in[7], Woff,
        bkv, x_hi, xlo_abf, wall, wob, bkv_p);

    // 1) fused input GEMM: q + interleaved kv + 3 offset segments (XCD-swizzled)
    gemm_fused<<<dim3(2304), blk, 0, stream>>>(
        x_hi, xlo_abf, wall, bq, bkv_p, boff, q_bf, kv, off1, off2, off3);

    // 2) sampling + attention with fused param prep -> a_bf (aliases x_lo)
    attn_sample<<<dim3((B_ * H_ * N_) / 16), blk, 0, stream>>>(
        q_bf, off1, off2, off3, kv, xlo_abf);

    // 3) out = attn @ Wo^T + bo (plain fp32 store, XCD-swizzled)
    gemm_out<<<dim3(512), blk, 0, stream>>>(xlo_abf, wob, bo, out);
}

// Round 13
// 168.316 us; speedup vs baseline: 1.1152x; 1.0131x over previous
//
#include <hip/hip_runtime.h>
#include <hip/hip_bf16.h>

// Problem constants (fixed by the reference module)
static constexpr int B_  = 2;
static constexpr int N_  = 4096;
static constexpr int D_  = 512;
static constexpr int H_  = 8;
static constexpr int P_  = 9;
static constexpr int GH_ = 16;   // grid h
static constexpr int GW_ = 256;  // grid w
static constexpr int M_  = B_ * N_;  // 8192 tokens

typedef __attribute__((ext_vector_type(8))) short bf16x8;
typedef __attribute__((ext_vector_type(4))) float f32x4;

__device__ __forceinline__ unsigned short f2b(float f) {
    __hip_bfloat16 h = __float2bfloat16(f);  // round-to-nearest
    return *reinterpret_cast<unsigned short*>(&h);
}
__device__ __forceinline__ float b2f(unsigned short u) {
    return __uint_as_float(((unsigned int)u) << 16);
}
__device__ __forceinline__ float b2f_lo(unsigned int u) { return __uint_as_float(u << 16); }
__device__ __forceinline__ float b2f_hi(unsigned int u) { return __uint_as_float(u & 0xffff0000u); }

// ---------------------------------------------------------------------------
// Cast fp32 -> bf16 and build the fused weight wall (2304 rows x 512):
//   rows 0..511 Wq | 512..1535 Wkv (ROW-PERMUTED to kv-interleaved layout) |
//   1536..1679 Woff_hi (pad->1791) | 1792..1935 Woff_lo (pad->2047) |
//   2048..2191 Woff_hi dup (pad->2303)
// kv-interleaved column c (in [0,1024)): head h=c>>7, w=c&127, g=w>>3, s=w&7;
//   s<4 -> k channel h*64+4g+s ; s>=4 -> v channel h*64+4g+(s-4).
// Also emits the matching permuted bias bkv_p[1024].
__global__ __launch_bounds__(256) void cast_multi(
    const float* __restrict__ x,   const float* __restrict__ wq,
    const float* __restrict__ wkv, const float* __restrict__ wo,
    const float* __restrict__ woff, const float* __restrict__ bkv,
    unsigned short* __restrict__ x_hi, unsigned short* __restrict__ x_lo,
    unsigned short* __restrict__ wall, unsigned short* __restrict__ wob,
    float* __restrict__ bkv_p) {
    int g = blockIdx.x * 256 + threadIdx.x;

    if (g < 1048576) {  // x -> hi + lo
        float4 v = reinterpret_cast<const float4*>(x)[g];
        ushort4 hi, lo;
        hi.x = f2b(v.x); hi.y = f2b(v.y); hi.z = f2b(v.z); hi.w = f2b(v.w);
        lo.x = f2b(v.x - b2f(hi.x)); lo.y = f2b(v.y - b2f(hi.y));
        lo.z = f2b(v.z - b2f(hi.z)); lo.w = f2b(v.w - b2f(hi.w));
        reinterpret_cast<ushort4*>(x_hi)[g] = hi;
        reinterpret_cast<ushort4*>(x_lo)[g] = lo;
        return;
    }
    g -= 1048576;
    if (g < 65536) {  // Wq -> wall rows 0..511
        float4 v = reinterpret_cast<const float4*>(wq)[g];
        ushort4 o; o.x = f2b(v.x); o.y = f2b(v.y); o.z = f2b(v.z); o.w = f2b(v.w);
        reinterpret_cast<ushort4*>(wall)[g] = o;
        return;
    }
    g -= 65536;
    if (g < 131072) {  // Wkv -> wall rows 512..1535, row-permuted
        const int r  = g >> 7;     // source row in Wkv (0..1023)
        const int c4 = g & 127;    // float4 index along K
        int pr;
        if (r < 512) {             // k row: channel h*64+c
            const int h = r >> 6, c = r & 63;
            pr = h * 128 + ((c >> 2) << 3) + (c & 3);
        } else {                   // v row
            const int r2 = r - 512;
            const int h = r2 >> 6, c = r2 & 63;
            pr = h * 128 + ((c >> 2) << 3) + 4 + (c & 3);
        }
        float4 v = reinterpret_cast<const float4*>(wkv)[g];
        ushort4 o; o.x = f2b(v.x); o.y = f2b(v.y); o.z = f2b(v.z); o.w = f2b(v.w);
        reinterpret_cast<ushort4*>(wall)[65536 + pr * 128 + c4] = o;
        return;
    }
    g -= 131072;
    if (g < 65536) {  // Wo -> wob
        float4 v = reinterpret_cast<const float4*>(wo)[g];
        ushort4 o; o.x = f2b(v.x); o.y = f2b(v.y); o.z = f2b(v.z); o.w = f2b(v.w);
        reinterpret_cast<ushort4*>(wob)[g] = o;
        return;
    }
    g -= 65536;
    if (g < 18432) {  // Woff rows 0..143 -> wall hi (1536), lo (1792), hi-dup (2048)
        float4 v = reinterpret_cast<const float4*>(woff)[g];
        ushort4 hi, lo;
        hi.x = f2b(v.x); hi.y = f2b(v.y); hi.z = f2b(v.z); hi.w = f2b(v.w);
        lo.x = f2b(v.x - b2f(hi.x)); lo.y = f2b(v.y - b2f(hi.y));
        lo.z = f2b(v.z - b2f(hi.z)); lo.w = f2b(v.w - b2f(hi.w));
        reinterpret_cast<ushort4*>(wall)[196608 + g] = hi;
        reinterpret_cast<ushort4*>(wall)[229376 + g] = lo;
        reinterpret_cast<ushort4*>(wall)[262144 + g] = hi;
        return;
    }
    g -= 18432;
    if (g < 43008) {  // zero pads: rows 1680..1791 / 1936..2047 / 2192..2303
        const int which = g / 14336;
        const int idx   = g - which * 14336;
        ushort4 z = {0, 0, 0, 0};
        reinterpret_cast<ushort4*>(wall)[215040 + which * 32768 + idx] = z;
        return;
    }
    g -= 43008;
    // permuted kv bias: g in [0,256), 4 channels each
#pragma unroll
    for (int t = 0; t < 4; ++t) {
        const int c = g * 4 + t;             // interleaved channel [0,1024)
        const int h = c >> 7, w = c & 127, gr = w >> 3, s = w & 7;
        const int orig = (s < 4) ? (h * 64 + gr * 4 + s)
                                 : (512 + h * 64 + gr * 4 + (s - 4));
        bkv_p[c] = bkv[orig];
    }
}

// ---------------------------------------------------------------------------
// MFMA K-loop. Tile 128(M) x 64(N), BK=64, LDS 24 KB.
// BANK-CONFLICT SWIZZLE: LDS slot s (16-B granule) of row r holds global slot
// s ^ (r & 3). Staging lane for linear slot gi = (r = gi>>2, s = gi&3) loads
// global col ((s ^ (r&3)) * 8); fragment reads use slot (lane>>4) ^ (R&3),
// and R&3 == lane&3 for every fragment row -> one per-lane constant fksw.
// Result: each 32-lane half touches all 8 bank-quads (4 lanes each) instead
// of 4 quads (8 lanes each) -> ds_read_b128 at structural minimum.
__device__ __forceinline__ void gemm_seg(const unsigned short* __restrict__ A,
                                         const unsigned short* __restrict__ W,
                                         int m0, int n0, int Kloop, int lda, int ldw,
                                         short* As, short* Bs,
                                         f32x4 (&acc)[4][2], int wave, int lane) {
    const int gi = wave * 64 + lane;        // [0,256)
    const int r0 = gi >> 2;
    const int c0 = ((gi & 3) ^ (r0 & 3)) * 8;   // swizzled source slot

    const unsigned short* pa0 = A + (size_t)(m0 + r0) * lda + c0;       // rows 0..63
    const unsigned short* pa1 = A + (size_t)(m0 + 64 + r0) * lda + c0;  // rows 64..127
    const unsigned short* pw  = W + (size_t)(n0 + r0) * ldw + c0;       // rows 0..63

    const int wm = wave & 1, wn = wave >> 1;
    const int fr = lane & 15;
    const int fksw = (((lane >> 4) ^ (lane & 3)) * 8);  // swizzled read slot

    for (int k0 = 0; k0 < Kloop; k0 += 64) {
#pragma unroll
        for (int t = 0; t < 2; ++t) {
            __builtin_amdgcn_global_load_lds(
                (const __attribute__((address_space(1))) void*)(pa0 + k0 + t * 32),
                (__attribute__((address_space(3))) void*)(As + t * 4096 + wave * 512),
                16, 0, 0);
            __builtin_amdgcn_global_load_lds(
                (const __attribute__((address_space(1))) void*)(pa1 + k0 + t * 32),
                (__attribute__((address_space(3))) void*)(As + t * 4096 + 2048 + wave * 512),
                16, 0, 0);
            __builtin_amdgcn_global_load_lds(
                (const __attribute__((address_space(1))) void*)(pw + k0 + t * 32),
                (__attribute__((address_space(3))) void*)(Bs + t * 2048 + wave * 512),
                16, 0, 0);
        }
        __syncthreads();

#pragma unroll
        for (int t = 0; t < 2; ++t) {
            bf16x8 af[4], bf[2];
#pragma unroll
            for (int i = 0; i < 4; ++i)
                af[i] = *reinterpret_cast<const bf16x8*>(
                    &As[t * 4096 + (wm * 64 + i * 16 + fr) * 32 + fksw]);
#pragma unroll
            for (int j = 0; j < 2; ++j)
                bf[j] = *reinterpret_cast<const bf16x8*>(
                    &Bs[t * 2048 + (wn * 32 + j * 16 + fr) * 32 + fksw]);
#pragma unroll
            for (int i = 0; i < 4; ++i)
#pragma unroll
                for (int j = 0; j < 2; ++j)
                    acc[i][j] = __builtin_amdgcn_mfma_f32_16x16x32_bf16(
                        af[i], bf[j], acc[i][j], 0, 0, 0);
        }
        __syncthreads();
    }
}

// ---------------------------------------------------------------------------
// Fused input GEMM, XCD-swizzled 1-D grid (2304 blocks).
// Work tiles: ty in [0,64) = 128-row M tile; tx in [0,36) = 64-col N tile:
//   0..7 q | 8..23 kv-interleaved | 24..27 off1(W_hi,x_hi) |
//   28..31 off2(W_lo,x_hi) | 32..35 off3(W_hi,x_lo).
// Swizzle: xcd=l&7, i=l>>3, ty=xcd+8*(i/36), tx=i%36 -> all 36 col tiles of a
// row tile dispatch to the same XCD; A tile stays in that XCD's L2.
__global__ __launch_bounds__(256, 3) void gemm_fused(
    const unsigned short* __restrict__ x_hi,
    const unsigned short* __restrict__ x_lo,
    const unsigned short* __restrict__ wall,
    const float* __restrict__ bq,
    const float* __restrict__ bkv_p,
    const float* __restrict__ boff,
    unsigned short* __restrict__ q_bf,
    unsigned short* __restrict__ kv,
    float* __restrict__ off1,
    float* __restrict__ off2,
    float* __restrict__ off3) {
    __shared__ short As[8192];  // 2 chunks x [128][32]
    __shared__ short Bs[4096];  // 2 chunks x [64][32]
    const int t = threadIdx.x;
    const int wave = t >> 6, lane = t & 63;

    const int l   = blockIdx.x;
    const int xcd = l & 7;
    const int i   = l >> 3;        // [0,288)
    const int iq  = i / 36;        // [0,8)
    const int tx  = i - iq * 36;   // [0,36)
    const int ty  = xcd + 8 * iq;  // [0,64)

    const int m0 = ty * 128;
    const int n0 = tx * 64;

    // x_lo pairs with the W_hi-dup segment (n >= 2048), i.e. col tiles 32..35.
    const unsigned short* A = (tx >= 32) ? x_lo : x_hi;

    f32x4 acc[4][2] = {};
    gemm_seg(A, wall, m0, n0, 512, 512, 512, As, Bs, acc, wave, lane);

    const int wm = wave & 1, wn = wave >> 1;
    const int ecol = lane & 15;
    const int erow = (lane >> 4) * 4;
#pragma unroll
    for (int i2 = 0; i2 < 4; ++i2) {
#pragma unroll
        for (int j = 0; j < 2; ++j) {
            const int n = n0 + wn * 32 + j * 16 + ecol;
#pragma unroll
            for (int r = 0; r < 4; ++r) {
                const int m = m0 + wm * 64 + i2 * 16 + erow + r;
                const float v = acc[i2][j][r];
                if (n < 512) {
                    q_bf[(size_t)m * 512 + n] = f2b((v + bq[n]) * 0.125f);
                } else if (n < 1536) {
                    kv[(size_t)m * 1024 + (n - 512)] = f2b(v + bkv_p[n - 512]);
                } else if (n < 1792) {
                    const int c = n - 1536;
                    if (c < 144) off1[(size_t)m * 144 + c] = v + boff[c];
                } else if (n < 2048) {
                    const int c = n - 1792;
                    if (c < 144) off2[(size_t)m * 144 + c] = v;
                } else {
                    const int c = n - 2048;
                    if (c < 144) off3[(size_t)m * 144 + c] = v;
                }
            }
        }
    }
}

// ---------------------------------------------------------------------------
// Out-projection GEMM, XCD-swizzled 1-D grid (512 blocks): xcd=l&7, i=l>>3,
// ty=xcd+8*(i>>3), tx=i&7. fp32 store + bias.
__global__ __launch_bounds__(256, 3) void gemm_out(
    const unsigned short* __restrict__ A,
    const unsigned short* __restrict__ W,
    const float* __restrict__ bias,
    float* __restrict__ out) {
    __shared__ short As[8192];
    __shared__ short Bs[4096];
    const int t = threadIdx.x;
    const int wave = t >> 6, lane = t & 63;

    const int l   = blockIdx.x;
    const int xcd = l & 7;
    const int i   = l >> 3;        // [0,64)
    const int tx  = i & 7;
    const int ty  = xcd + 8 * (i >> 3);

    const int m0 = ty * 128;
    const int n0 = tx * 64;

    f32x4 acc[4][2] = {};
    gemm_seg(A, W, m0, n0, 512, 512, 512, As, Bs, acc, wave, lane);

    const int wm = wave & 1, wn = wave >> 1;
    const int ecol = lane & 15;
    const int erow = (lane >> 4) * 4;
#pragma unroll
    for (int i2 = 0; i2 < 4; ++i2) {
#pragma unroll
        for (int j = 0; j < 2; ++j) {
            const int n = n0 + wn * 32 + j * 16 + ecol;
            const float bb = bias[n];
#pragma unroll
            for (int r = 0; r < 4; ++r) {
                const int m = m0 + wm * 64 + i2 * 16 + erow + r;
                out[(size_t)m * 512 + n] = acc[i2][j][r] + bb;
            }
        }
    }
}

// ---------------------------------------------------------------------------
// Sampling + attention, with inlined parameter computation.
// XCD swizzle: bsw=(l&7)*512+(l>>3) -> each XCD owns contiguous token ranges.
// One wave = 4 consecutive tokens of one (b, head); 16 lanes per token, lane j
// covers channels 4j..4j+3 via ONE uint4 per corner from the kv-interleaved
// plane. Lanes 0..35 first compute the wave's 4x9 sampling params into LDS.
__global__ __launch_bounds__(256) void attn_sample(const unsigned short* __restrict__ q_bf,
                                                   const float* __restrict__ off1,
                                                   const float* __restrict__ off2,
                                                   const float* __restrict__ off3,
                                                   const unsigned short* __restrict__ kv,
                                                   unsigned short* __restrict__ a_bf) {
    __shared__ float4 pw_s[4][36];
    __shared__ int4   po_s[4][36];

    const int lane = threadIdx.x & 63;
    const int wave = threadIdx.x >> 6;
    const int quarter = lane >> 4;
    const int j    = lane & 15;
    const int bsw  = (blockIdx.x & 7) * 512 + (blockIdx.x >> 3);  // [0,4096)
    const int wid  = bsw * 4 + wave;  // [0, 16384)
    const int b    = wid >> 13;
    const int hh   = (wid >> 10) & 7;
    const int nq   = wid & 1023;
    const int n    = nq * 4 + quarter;

    // ---- parameter computation: lane l < 36 handles (qt = l/9, p = l%9) ----
    if (lane < 36) {
        const int qt = lane / 9;
        const int p  = lane - qt * 9;
        const int tn = nq * 4 + qt;
        const size_t tokq = (size_t)b * N_ + tn;
        const size_t oidx = tokq * 144 + hh * 18 + 2 * p;
        const float2 a1 = *reinterpret_cast<const float2*>(off1 + oidx);
        const float2 a2 = *reinterpret_cast<const float2*>(off2 + oidx);
        const float2 a3 = *reinterpret_cast<const float2*>(off3 + oidx);
        const float dx = tanhf(a1.x + a2.x + a3.x) * 4.0f;
        const float dy = tanhf(a1.y + a2.y + a3.y) * 4.0f;
        const float sx = (float)(tn & (GW_ - 1)) + dx;
        const float sy = (float)(tn >> 8) + dy;
        const float x0f = floorf(sx), y0f = floorf(sy);
        const int x0 = (int)x0f, y0 = (int)y0f;
        const float wx1 = sx - x0f, wy1 = sy - y0f;
        const float wx0 = 1.0f - wx1, wy0 = 1.0f - wy1;

        float4 w;
        int4 ro;
        {
            const int xi = x0, yi = y0;
            const bool v = (xi >= 0) & (xi < GW_) & (yi >= 0) & (yi < GH_);
            w.x = v ? wx0 * wy0 : 0.0f;
            const int xc = xi < 0 ? 0 : (xi > 255 ? 255 : xi);
            const int yc = yi < 0 ? 0 : (yi > 15 ? 15 : yi);
            ro.x = (yc * GW_ + xc) * 1024 + hh * 128;
        }
        {
            const int xi = x0 + 1, yi = y0;
            const bool v = (xi >= 0) & (xi < GW_) & (yi >= 0) & (yi < GH_);
            w.y = v ? wx1 * wy0 : 0.0f;
            const int xc = xi < 0 ? 0 : (xi > 255 ? 255 : xi);
            const int yc = yi < 0 ? 0 : (yi > 15 ? 15 : yi);
            ro.y = (yc * GW_ + xc) * 1024 + hh * 128;
        }
        {
            const int xi = x0, yi = y0 + 1;
            const bool v = (xi >= 0) & (xi < GW_) & (yi >= 0) & (yi < GH_);
            w.z = v ? wx0 * wy1 : 0.0f;
            const int xc = xi < 0 ? 0 : (xi > 255 ? 255 : xi);
            const int yc = yi < 0 ? 0 : (yi > 15 ? 15 : yi);
            ro.z = (yc * GW_ + xc) * 1024 + hh * 128;
        }
        {
            const int xi = x0 + 1, yi = y0 + 1;
            const bool v = (xi >= 0) & (xi < GW_) & (yi >= 0) & (yi < GH_);
            w.w = v ? wx1 * wy1 : 0.0f;
            const int xc = xi < 0 ? 0 : (xi > 255 ? 255 : xi);
            const int yc = yi < 0 ? 0 : (yi > 15 ? 15 : yi);
            ro.w = (yc * GW_ + xc) * 1024 + hh * 128;
        }
        pw_s[wave][lane] = w;
        po_s[wave][lane] = ro;
    }
    __syncthreads();

    // ---- sampling + attention ----
    const size_t tok = (size_t)b * N_ + n;
    const uint2 qp = *reinterpret_cast<const uint2*>(
        q_bf + tok * 512 + hh * 64 + 4 * j);
    const float q0 = b2f_lo(qp.x), q1 = b2f_hi(qp.x);
    const float q2 = b2f_lo(qp.y), q3 = b2f_hi(qp.y);

    const unsigned short* kvbase = kv + (size_t)b * (N_ * 1024) + 8 * j;
    const int ebase = quarter * 9;

    float lg[9], s0[9], s1[9], s2[9], s3[9];
    float mx = -1e30f;

#pragma unroll
    for (int p = 0; p < P_; ++p) {
        const float4 w = pw_s[wave][ebase + p];
        const int4 ro = po_s[wave][ebase + p];
        float k0 = 0.f, k1 = 0.f, k2 = 0.f, k3 = 0.f;
        float v0 = 0.f, v1 = 0.f, v2 = 0.f, v3 = 0.f;
#pragma unroll
        for (int c = 0; c < 4; ++c) {
            const int r = (c == 0) ? ro.x : (c == 1) ? ro.y : (c == 2) ? ro.z : ro.w;
            const float wgt = (c == 0) ? w.x : (c == 1) ? w.y : (c == 2) ? w.z : w.w;
            const uint4 u = *reinterpret_cast<const uint4*>(kvbase + r);
            k0 = fmaf(wgt, b2f_lo(u.x), k0); k1 = fmaf(wgt, b2f_hi(u.x), k1);
            k2 = fmaf(wgt, b2f_lo(u.y), k2); k3 = fmaf(wgt, b2f_hi(u.y), k3);
            v0 = fmaf(wgt, b2f_lo(u.z), v0); v1 = fmaf(wgt, b2f_hi(u.z), v1);
            v2 = fmaf(wgt, b2f_lo(u.w), v2); v3 = fmaf(wgt, b2f_hi(u.w), v3);
        }
        float ts = fmaf(q0, k0, fmaf(q1, k1, fmaf(q2, k2, q3 * k3)));
#pragma unroll
        for (int s = 8; s > 0; s >>= 1) ts += __shfl_xor(ts, s, 64);  // 16-lane group
        lg[p] = ts;
        s0[p] = v0; s1[p] = v1; s2[p] = v2; s3[p] = v3;
        mx = fmaxf(mx, lg[p]);
    }

    float ssum = 0.f, o0 = 0.f, o1 = 0.f, o2 = 0.f, o3 = 0.f;
#pragma unroll
    for (int p = 0; p < P_; ++p) {
        const float e = __expf(lg[p] - mx);
        ssum += e;
        o0 = fmaf(e, s0[p], o0);
        o1 = fmaf(e, s1[p], o1);
        o2 = fmaf(e, s2[p], o2);
        o3 = fmaf(e, s3[p], o3);
    }
    const float rs = 1.0f / ssum;
    uint2 pack;
    pack.x = (unsigned int)f2b(o0 * rs) | ((unsigned int)f2b(o1 * rs) << 16);
    pack.y = (unsigned int)f2b(o2 * rs) | ((unsigned int)f2b(o3 * rs) << 16);
    *reinterpret_cast<uint2*>(a_bf + tok * 512 + hh * 64 + 4 * j) = pack;
}

// ---------------------------------------------------------------------------
extern "C" void kernel_launch(void* const* d_in, const int* in_sizes, int n_in,
                              void* d_out, int out_size, void* d_ws, size_t ws_size,
                              hipStream_t stream) {
    const float* x    = (const float*)d_in[0];
    const float* bq   = (const float*)d_in[2];
    const float* Woff = (const float*)d_in[3];
    const float* boff = (const float*)d_in[4];
    const float* bkv  = (const float*)d_in[6];
    const float* bo   = (const float*)d_in[8];
    float* out = (float*)d_out;

    // Workspace layout (~57 MB)
    char* ws = (char*)d_ws;
    unsigned short* q_bf    = (unsigned short*)ws; ws += (size_t)M_ * 512 * 2;     // 8 MB
    unsigned short* kv      = (unsigned short*)ws; ws += (size_t)M_ * 1024 * 2;    // 16.8 MB
    float*          off1    = (float*)ws;          ws += (size_t)M_ * 144 * 4;     // 4.7 MB
    float*          off2    = (float*)ws;          ws += (size_t)M_ * 144 * 4;     // 4.7 MB
    float*          off3    = (float*)ws;          ws += (size_t)M_ * 144 * 4;     // 4.7 MB
    unsigned short* xlo_abf = (unsigned short*)ws; ws += (size_t)M_ * 512 * 2;     // 8 MB (x_lo, then a_bf)
    unsigned short* x_hi    = (unsigned short*)ws; ws += (size_t)M_ * 512 * 2;     // 8 MB
    unsigned short* wall    = (unsigned short*)ws; ws += (size_t)2304 * 512 * 2;   // 2.4 MB
    unsigned short* wob     = (unsigned short*)ws; ws += (size_t)512 * 512 * 2;    // 0.5 MB
    float*          bkv_p   = (float*)ws;          ws += (size_t)1024 * 4;         // 4 KB

    const dim3 blk(256);

    // 0) casts (x -> hi/lo, weight wall w/ kv row permutation, wo, bias perm)
    cast_multi<<<dim3(5361), blk, 0, stream>>>(
        x, (const float*)d_in[1], (const float*)d_in[5], (const float*)d_in[7], Woff,
        bkv, x_hi, xlo_abf, wall, wob, bkv_p);

    // 1) fused input GEMM: q + interleaved kv + 3 offset segments (XCD-swizzled)
    gemm_fused<<<dim3(2304), blk, 0, stream>>>(
        x_hi, xlo_abf, wall, bq, bkv_p, boff, q_bf, kv, off1, off2, off3);

    // 2) sampling + attention with fused param prep -> a_bf (aliases x_lo)
    attn_sample<<<dim3((B_ * H_ * N_) / 16), blk, 0, stream>>>(
        q_bf, off1, off2, off3, kv, xlo_abf);

    // 3) out = attn @ Wo^T + bo (plain fp32 store, XCD-swizzled)
    gemm_out<<<dim3(512), blk, 0, stream>>>(xlo_abf, wob, bo, out);
}